// Round 1
// baseline (156.028 us; speedup 1.0000x reference)
//
#include <hip/hip_runtime.h>
#include <hip/hip_bf16.h>

#define NDOM 8
#define BK 32
#define LSTR 40  // 32 k-elems + 8 pad (bf16) -> row stride 80 B, 16B-aligned

typedef short short8 __attribute__((ext_vector_type(8)));
typedef float f32x4 __attribute__((ext_vector_type(4)));

__device__ inline unsigned short f2bf(float f) {
    unsigned u = __float_as_uint(f);
    u = (u + 0x7FFFu + ((u >> 16) & 1u)) >> 16;  // round-to-nearest-even
    return (unsigned short)u;
}

// ---------------------------------------------------------------- bucket ----
// Single block: count labels, prefix-sum offsets, scatter permutation.
// Also zeroes the per-domain pair-sum accumulators (ws is poisoned 0xAA).
__global__ void k_bucket(const int* __restrict__ labels, int B,
                         int* __restrict__ perm, int* __restrict__ dom_off,
                         int* __restrict__ counts, float* __restrict__ pair_sums) {
    __shared__ int cnt[NDOM], offs[NDOM + 1], cur[NDOM];
    int t = threadIdx.x;
    if (t < NDOM) cnt[t] = 0;
    __syncthreads();
    for (int i = t; i < B; i += blockDim.x) atomicAdd(&cnt[labels[i]], 1);
    __syncthreads();
    if (t == 0) {
        offs[0] = 0;
        for (int d = 0; d < NDOM; ++d) offs[d + 1] = offs[d] + cnt[d];
    }
    __syncthreads();
    if (t < NDOM) {
        cur[t] = offs[t];
        counts[t] = cnt[t];
        pair_sums[t] = 0.f;
    }
    if (t <= NDOM) dom_off[t] = offs[t];
    __syncthreads();
    for (int i = t; i < B; i += blockDim.x) {
        int d = labels[i];
        int pos = atomicAdd(&cur[d], 1);
        perm[pos] = i;
    }
}

// ---------------------------------------------------------------- gather ----
// One block per grouped row p: gather F[perm[p]], convert to bf16, row norm^2.
__global__ void k_gather(const float* __restrict__ F, const int* __restrict__ perm,
                         unsigned short* __restrict__ Fb, float* __restrict__ sq,
                         int K) {
    int p = blockIdx.x;
    int i = perm[p];
    int t = threadIdx.x;
    const float4* src = (const float4*)(F + (size_t)i * K);
    ushort4* dst = (ushort4*)(Fb + (size_t)p * K);
    float ss = 0.f;
    int nv = K >> 2;
    for (int c = t; c < nv; c += blockDim.x) {
        float4 v = src[c];
        ushort4 o;
        o.x = f2bf(v.x); o.y = f2bf(v.y); o.z = f2bf(v.z); o.w = f2bf(v.w);
        dst[c] = o;
        ss += v.x * v.x + v.y * v.y + v.z * v.z + v.w * v.w;
    }
    __shared__ float red[256];
    red[t] = ss;
    __syncthreads();
    for (int s = 128; s > 0; s >>= 1) {
        if (t < s) red[t] += red[t + s];
        __syncthreads();
    }
    if (t == 0) sq[p] = red[0];
}

// ------------------------------------------------------------------ gram ----
// Per-domain 128x128 tile: bf16 MFMA Gram + fused relu(1-dist) epilogue.
// 256 threads = 4 waves (2x2), each wave 64x64 = 4x4 subtiles of 16x16x32.
__global__ __launch_bounds__(256) void k_gram(
    const unsigned short* __restrict__ Fb, const float* __restrict__ sq,
    const int* __restrict__ dom_off, float* __restrict__ pair_sums, int K) {
    int dom = blockIdx.z;
    int off = dom_off[dom];
    int n = dom_off[dom + 1] - off;
    int tr = blockIdx.y * 128, tc = blockIdx.x * 128;
    if (tr >= n || tc >= n) return;  // uniform early-exit (before any barrier)

    __shared__ unsigned short lA[128 * LSTR], lB[128 * LSTR];
    __shared__ float sqA[128], sqB[128];
    __shared__ float red[256];

    int t = threadIdx.x;
    if (t < 128) sqA[t] = sq[off + min(tr + t, n - 1)];
    else         sqB[t - 128] = sq[off + min(tc + (t - 128), n - 1)];

    int lane = t & 63, wv = t >> 6;
    int wm = (wv & 1) * 64, wn = (wv >> 1) * 64;
    int m16 = lane & 15, quad = lane >> 4;

    f32x4 acc[4][4];
#pragma unroll
    for (int im = 0; im < 4; ++im)
#pragma unroll
        for (int in = 0; in < 4; ++in) acc[im][in] = (f32x4){0.f, 0.f, 0.f, 0.f};

    for (int kb = 0; kb < K; kb += BK) {
        __syncthreads();
#pragma unroll
        for (int half = 0; half < 2; ++half) {
            int idx = half * 256 + t;       // 0..511: 128 rows x 4 chunks of 8
            int row = idx >> 2, c8 = (idx & 3) * 8;
            size_t ga = (size_t)(off + min(tr + row, n - 1)) * K + kb + c8;
            size_t gb = (size_t)(off + min(tc + row, n - 1)) * K + kb + c8;
            *(uint4*)(&lA[row * LSTR + c8]) = *(const uint4*)(Fb + ga);
            *(uint4*)(&lB[row * LSTR + c8]) = *(const uint4*)(Fb + gb);
        }
        __syncthreads();
        short8 af[4], bf[4];
#pragma unroll
        for (int im = 0; im < 4; ++im)
            af[im] = *(const short8*)(&lA[(wm + im * 16 + m16) * LSTR + quad * 8]);
#pragma unroll
        for (int in = 0; in < 4; ++in)
            bf[in] = *(const short8*)(&lB[(wn + in * 16 + m16) * LSTR + quad * 8]);
#pragma unroll
        for (int im = 0; im < 4; ++im)
#pragma unroll
            for (int in = 0; in < 4; ++in)
                acc[im][in] = __builtin_amdgcn_mfma_f32_16x16x32_bf16(
                    af[im], bf[in], acc[im][in], 0, 0, 0);
    }

    // epilogue: D[row=quad*4+reg][col=lane&15] per 16x16 subtile
    float local = 0.f;
#pragma unroll
    for (int im = 0; im < 4; ++im) {
        int pr0 = tr + wm + im * 16 + quad * 4;
#pragma unroll
        for (int in = 0; in < 4; ++in) {
            int pc = tc + wn + in * 16 + m16;
#pragma unroll
            for (int r = 0; r < 4; ++r) {
                int pr = pr0 + r;
                if (pr < n && pc < n) {
                    float val;
                    if (pr == pc) {
                        val = 1.0f;  // exact: dist(i,i) == 0
                    } else {
                        float d2 = sqA[pr - tr] + sqB[pc - tc] - 2.0f * acc[im][in][r];
                        d2 = fmaxf(d2, 0.f);
                        val = fmaxf(1.0f - sqrtf(d2), 0.f);
                    }
                    local += val;
                }
            }
        }
    }
    red[t] = local;
    __syncthreads();
    for (int s = 128; s > 0; s >>= 1) {
        if (t < s) red[t] += red[t + s];
        __syncthreads();
    }
    if (t == 0) atomicAdd(&pair_sums[dom], red[0]);
}

// -------------------------------------------------------------- finalize ----
__global__ void k_final(const float* __restrict__ pair_sums,
                        const int* __restrict__ counts, float* __restrict__ out) {
    if (threadIdx.x == 0) {
        float s = 0.f;
        int v = 0;
        for (int d = 0; d < NDOM; ++d) {
            int n = counts[d];
            if (n > 1) {
                s += pair_sums[d] / ((float)n * (float)n);
                ++v;
            }
        }
        out[0] = (v > 0) ? s / (float)v : 0.f;
    }
}

// ---------------------------------------------------------------- launch ----
extern "C" void kernel_launch(void* const* d_in, const int* in_sizes, int n_in,
                              void* d_out, int out_size, void* d_ws, size_t ws_size,
                              hipStream_t stream) {
    const float* F = (const float*)d_in[0];
    const int* labels = (const int*)d_in[1];
    int B = in_sizes[1];
    int K = in_sizes[0] / B;  // 4096, 1024

    char* ws = (char*)d_ws;
    size_t o = 0;
    unsigned short* Fb = (unsigned short*)(ws + o);
    o += (size_t)B * K * sizeof(unsigned short);
    o = (o + 255) & ~(size_t)255;
    float* sq = (float*)(ws + o);
    o += (size_t)B * sizeof(float);
    o = (o + 255) & ~(size_t)255;
    int* perm = (int*)(ws + o);
    o += (size_t)B * sizeof(int);
    o = (o + 255) & ~(size_t)255;
    int* dom_off = (int*)(ws + o);
    o += (NDOM + 1) * sizeof(int);
    o = (o + 255) & ~(size_t)255;
    int* counts = (int*)(ws + o);
    o += NDOM * sizeof(int);
    o = (o + 255) & ~(size_t)255;
    float* pair_sums = (float*)(ws + o);

    k_bucket<<<1, 256, 0, stream>>>(labels, B, perm, dom_off, counts, pair_sums);
    k_gather<<<B, 256, 0, stream>>>(F, perm, Fb, sq, K);
    int nt = (B + 127) / 128;  // worst case: one domain owns all rows
    k_gram<<<dim3(nt, nt, NDOM), 256, 0, stream>>>(Fb, sq, dom_off, pair_sums, K);
    k_final<<<1, 64, 0, stream>>>(pair_sums, counts, (float*)d_out);
}

// Round 2
// 131.082 us; speedup vs baseline: 1.1903x; 1.1903x over previous
//
#include <hip/hip_runtime.h>
#include <hip/hip_bf16.h>

#define NDOM 8
#define TM 64   // tile (rows == cols)
#define BK 64   // k-slice per LDS stage

typedef short short8 __attribute__((ext_vector_type(8)));
typedef float f32x4 __attribute__((ext_vector_type(4)));

__device__ inline unsigned short f2bf(float f) {
    unsigned u = __float_as_uint(f);
    u = (u + 0x7FFFu + ((u >> 16) & 1u)) >> 16;  // RNE
    return (unsigned short)u;
}

__device__ inline void gload16(const void* g, void* l) {
    __builtin_amdgcn_global_load_lds(
        (const __attribute__((address_space(1))) unsigned int*)g,
        (__attribute__((address_space(3))) unsigned int*)l, 16, 0, 0);
}

// ---------------------------------------------------------------- bucket ----
// 256 threads = 4 waves. Atomic-free: ballot/popc ranking per 64-chunk,
// per-wave counts combined through tiny LDS. ~3 us vs ~50 us of LDS atomics.
__global__ void k_bucket(const int* __restrict__ labels, int B,
                         int* __restrict__ perm, int* __restrict__ dom_off,
                         int* __restrict__ counts, float* __restrict__ pair_sums) {
    __shared__ unsigned wcnt[4][NDOM];
    int t = threadIdx.x, lane = t & 63, wv = t >> 6;
    int nch = (B + 63) >> 6;
    int cpw = (nch + 3) >> 2;
    int c0 = wv * cpw, c1 = min(c0 + cpw, nch);
    unsigned long long below = (1ull << lane) - 1ull;

    unsigned cnt[NDOM];
#pragma unroll
    for (int d = 0; d < NDOM; ++d) cnt[d] = 0;
    for (int c = c0; c < c1; ++c) {
        int i = c * 64 + lane;
        int d = (i < B) ? labels[i] : -1;
#pragma unroll
        for (int dd = 0; dd < NDOM; ++dd)
            cnt[dd] += (unsigned)__popcll(__ballot(d == dd));
    }
    if (lane == 0)
#pragma unroll
        for (int dd = 0; dd < NDOM; ++dd) wcnt[wv][dd] = cnt[dd];
    __syncthreads();

    unsigned tot[NDOM], offs[NDOM + 1];
    offs[0] = 0;
#pragma unroll
    for (int dd = 0; dd < NDOM; ++dd) {
        tot[dd] = wcnt[0][dd] + wcnt[1][dd] + wcnt[2][dd] + wcnt[3][dd];
        offs[dd + 1] = offs[dd] + tot[dd];
    }
    if (t < NDOM) { counts[t] = (int)tot[t]; pair_sums[t] = 0.f; }
    if (t <= NDOM) dom_off[t] = (int)offs[t];

    unsigned run[NDOM];
#pragma unroll
    for (int dd = 0; dd < NDOM; ++dd) {
        unsigned base = offs[dd];
        for (int w = 0; w < 4; ++w)
            if (w < wv) base += wcnt[w][dd];
        run[dd] = base;
    }
    for (int c = c0; c < c1; ++c) {
        int i = c * 64 + lane;
        int d = (i < B) ? labels[i] : -1;
        int pos = -1;
#pragma unroll
        for (int dd = 0; dd < NDOM; ++dd) {
            unsigned long long m = __ballot(d == dd);
            if (d == dd) pos = (int)run[dd] + __popcll(m & below);
            run[dd] += (unsigned)__popcll(m);
        }
        if (i < B) perm[pos] = i;
    }
}

// ---------------------------------------------------------------- gather ----
// 4 rows/block, one wave per row; fp32 -> bf16 + ||f||^2 via shuffle reduce.
__global__ void k_gather(const float* __restrict__ F, const int* __restrict__ perm,
                         unsigned short* __restrict__ Fb, float* __restrict__ sq,
                         int B, int K) {
    int wv = threadIdx.x >> 6, lane = threadIdx.x & 63;
    int p = blockIdx.x * 4 + wv;
    if (p >= B) return;
    int i = perm[p];
    const float4* src = (const float4*)(F + (size_t)i * K);
    ushort4* dst = (ushort4*)(Fb + (size_t)p * K);
    float ss = 0.f;
    int nv = K >> 2;
    for (int c = lane; c < nv; c += 64) {
        float4 v = src[c];
        ushort4 o;
        o.x = f2bf(v.x); o.y = f2bf(v.y); o.z = f2bf(v.z); o.w = f2bf(v.w);
        dst[c] = o;
        ss += v.x * v.x + v.y * v.y + v.z * v.z + v.w * v.w;
    }
#pragma unroll
    for (int s = 32; s > 0; s >>= 1) ss += __shfl_xor(ss, s);
    if (lane == 0) sq[p] = ss;
}

// ------------------------------------------------------------------ gram ----
// Persistent blocks over a flattened per-domain tile list. 64x64 tiles,
// BK=64, global_load_lds (16B) staging with XOR chunk swizzle done on the
// global-address side (LDS dst stays wave-uniform-base + lane*16).
// 4 waves, each 32x32 = 2x2 subtiles of 16x16x32 bf16 MFMA.
__global__ __launch_bounds__(256) void k_gram(
    const unsigned short* __restrict__ Fb, const float* __restrict__ sq,
    const int* __restrict__ dom_off, float* __restrict__ pair_sums, int K) {
    __shared__ unsigned short lA[TM * BK], lB[TM * BK];  // 8 KB each
    __shared__ int s_offs[NDOM + 1], s_tstart[NDOM + 1];

    int t = threadIdx.x, lane = t & 63, wv = t >> 6;
    int m16 = lane & 15, quad = lane >> 4;
    int wm = (wv & 1) * 32, wn = (wv >> 1) * 32;

    if (t == 0) {
        int T = 0;
        for (int d = 0; d < NDOM; ++d) {
            s_offs[d] = dom_off[d];
            s_tstart[d] = T;
            int n = dom_off[d + 1] - dom_off[d];
            int nt = (n + TM - 1) / TM;
            T += nt * nt;
        }
        s_offs[NDOM] = dom_off[NDOM];
        s_tstart[NDOM] = T;
    }
    __syncthreads();
    int T = s_tstart[NDOM];

    // per-lane staging decode (constant across tiles/kb):
    // instruction h covers tile rows [wv*16+h*8, +8); lane -> row r, slot s.
    // LDS slot(r,c) = r*8 + ((c ^ (r>>1)) & 7)  => chunk c = (s ^ (r>>1)) & 7.
    int rl[2], cl[2];
#pragma unroll
    for (int h = 0; h < 2; ++h) {
        rl[h] = wv * 16 + h * 8 + (lane >> 3);
        cl[h] = ((lane & 7) ^ (rl[h] >> 1)) & 7;
    }

    for (int tile = blockIdx.x; tile < T; tile += gridDim.x) {
        int dom = 0;
        while (tile >= s_tstart[dom + 1]) ++dom;
        int off = s_offs[dom], n = s_offs[dom + 1] - off;
        int nt = (n + TM - 1) / TM;
        int rel = tile - s_tstart[dom];
        int ty = rel / nt, tx = rel - ty * nt;
        int tr = ty * TM, tc = tx * TM;

        // hoisted per-lane global base pointers for the 4 staging instrs
        const unsigned short* gA[2];
        const unsigned short* gB[2];
#pragma unroll
        for (int h = 0; h < 2; ++h) {
            gA[h] = Fb + (size_t)(off + min(tr + rl[h], n - 1)) * K + cl[h] * 8;
            gB[h] = Fb + (size_t)(off + min(tc + rl[h], n - 1)) * K + cl[h] * 8;
        }

        f32x4 acc[2][2];
#pragma unroll
        for (int im = 0; im < 2; ++im)
#pragma unroll
            for (int in = 0; in < 2; ++in) acc[im][in] = (f32x4){0.f, 0.f, 0.f, 0.f};

        for (int kb = 0; kb < K; kb += BK) {
#pragma unroll
            for (int h = 0; h < 2; ++h) {
                int ldso = (wv * 16 + h * 8) * BK;  // ushort offset of 8-row group
                gload16(gA[h] + kb, lA + ldso);
                gload16(gB[h] + kb, lB + ldso);
            }
            __syncthreads();  // drains vmcnt before barrier -> LDS data visible
#pragma unroll
            for (int ks = 0; ks < 2; ++ks) {
                short8 af[2], bg[2];
#pragma unroll
                for (int im = 0; im < 2; ++im) {
                    int r = wm + im * 16 + m16;
                    int c = ks * 4 + quad;
                    int slot = r * 8 + ((c ^ (r >> 1)) & 7);
                    af[im] = *(const short8*)(lA + slot * 8);
                }
#pragma unroll
                for (int in = 0; in < 2; ++in) {
                    int r = wn + in * 16 + m16;
                    int c = ks * 4 + quad;
                    int slot = r * 8 + ((c ^ (r >> 1)) & 7);
                    bg[in] = *(const short8*)(lB + slot * 8);
                }
#pragma unroll
                for (int im = 0; im < 2; ++im)
#pragma unroll
                    for (int in = 0; in < 2; ++in)
                        acc[im][in] = __builtin_amdgcn_mfma_f32_16x16x32_bf16(
                            af[im], bg[in], acc[im][in], 0, 0, 0);
            }
            __syncthreads();  // all reads done before next-stage overwrite
        }

        // epilogue: D[row=quad*4+r][col=m16] per subtile; relu(1-dist)
        float local = 0.f;
#pragma unroll
        for (int im = 0; im < 2; ++im) {
            int pr0 = tr + wm + im * 16 + quad * 4;
#pragma unroll
            for (int in = 0; in < 2; ++in) {
                int pc = tc + wn + in * 16 + m16;
                float sb = (pc < n) ? sq[off + pc] : 0.f;
#pragma unroll
                for (int r = 0; r < 4; ++r) {
                    int pr = pr0 + r;
                    if (pr < n && pc < n) {
                        float val;
                        if (pr == pc) {
                            val = 1.0f;  // exact: dist(i,i) == 0
                        } else {
                            float d2 = sq[off + pr] + sb - 2.0f * acc[im][in][r];
                            d2 = fmaxf(d2, 0.f);
                            val = fmaxf(1.0f - sqrtf(d2), 0.f);
                        }
                        local += val;
                    }
                }
            }
        }
#pragma unroll
        for (int s = 32; s > 0; s >>= 1) local += __shfl_xor(local, s);
        if (lane == 0) atomicAdd(&pair_sums[dom], local);
    }
}

// -------------------------------------------------------------- finalize ----
__global__ void k_final(const float* __restrict__ pair_sums,
                        const int* __restrict__ counts, float* __restrict__ out) {
    if (threadIdx.x == 0) {
        float s = 0.f;
        int v = 0;
        for (int d = 0; d < NDOM; ++d) {
            int n = counts[d];
            if (n > 1) {
                s += pair_sums[d] / ((float)n * (float)n);
                ++v;
            }
        }
        out[0] = (v > 0) ? s / (float)v : 0.f;
    }
}

// ---------------------------------------------------------------- launch ----
extern "C" void kernel_launch(void* const* d_in, const int* in_sizes, int n_in,
                              void* d_out, int out_size, void* d_ws, size_t ws_size,
                              hipStream_t stream) {
    const float* F = (const float*)d_in[0];
    const int* labels = (const int*)d_in[1];
    int B = in_sizes[1];
    int K = in_sizes[0] / B;  // 4096, 1024

    char* ws = (char*)d_ws;
    size_t o = 0;
    unsigned short* Fb = (unsigned short*)(ws + o);
    o += (size_t)B * K * sizeof(unsigned short);
    o = (o + 255) & ~(size_t)255;
    float* sq = (float*)(ws + o);
    o += (size_t)B * sizeof(float);
    o = (o + 255) & ~(size_t)255;
    int* perm = (int*)(ws + o);
    o += (size_t)B * sizeof(int);
    o = (o + 255) & ~(size_t)255;
    int* dom_off = (int*)(ws + o);
    o += (NDOM + 1) * sizeof(int);
    o = (o + 255) & ~(size_t)255;
    int* counts = (int*)(ws + o);
    o += NDOM * sizeof(int);
    o = (o + 255) & ~(size_t)255;
    float* pair_sums = (float*)(ws + o);

    k_bucket<<<1, 256, 0, stream>>>(labels, B, perm, dom_off, counts, pair_sums);
    k_gather<<<(B + 3) / 4, 256, 0, stream>>>(F, perm, Fb, sq, B, K);
    k_gram<<<512, 256, 0, stream>>>(Fb, sq, dom_off, pair_sums, K);
    k_final<<<1, 64, 0, stream>>>(pair_sums, counts, (float*)d_out);
}